// Round 6
// baseline (173.630 us; speedup 1.0000x reference)
//
#include <hip/hip_runtime.h>
#include <math.h>

#define B_ 32
#define H_ 112
#define W_ 112
#define C_ 192
#define C4 (C_/4)              // 48
#define R_ 7                   // output rows per block
#define TPI (H_/R_)            // 16 tiles per image
#define NBLK (B_*TPI)          // 512 blocks = exactly 2 per CU
#define HALO 3
#define SR (R_ + 2*HALO)       // 13 staged (avg,max) rows
#define SW (W_ + 2*HALO)       // 118 staged cols
#define SWP 120                // padded LDS width
#define NT_ 1024

typedef float nf4 __attribute__((ext_vector_type(4)));

// Fused 3-phase kernel, occupancy-engineered: 512 blocks (2/CU, balanced),
// 1024 threads (32 waves/CU), VGPR capped at 64 so 8 waves/SIMD materialize.
// Phase 1: channel avg/max of the 13-row halo window -> LDS.
// Phase 2: 7x7 conv + sigmoid in LDS (no global ws2/att at all).
// Phase 3: re-read own 7 x-rows (short reuse distance -> L2/L3 hit) * att.
__global__ __launch_bounds__(NT_, 8) void fused_kernel(const float* __restrict__ x,
                                                       const float* __restrict__ w,
                                                       float* __restrict__ out) {
    __shared__ float2 sm[SR][SWP];    // 12.5 KB
    __shared__ float  sw[98];
    __shared__ float  satt[R_ * W_];  // 3.1 KB

    const int tid = threadIdx.x;
    // XCD swizzle: consecutive blockIdx round-robin across 8 XCDs; remap so
    // each XCD owns a contiguous span of 64 tiles (adjacent tiles share L2).
    const int bid = ((int)blockIdx.x & 7) * (NBLK / 8) + ((int)blockIdx.x >> 3);
    const int b   = bid / TPI;
    const int t   = bid - b * TPI;
    const int y0  = t * R_;

    if (tid < 98) sw[tid] = w[tid];
    for (int i = tid; i < SR * SWP; i += NT_)
        ((float2*)sm)[i] = make_float2(0.0f, 0.0f);
    __syncthreads();

    // ---- phase 1: channel mean/max, 64 groups x 16 lanes, 3 float4/lane ----
    const int g   = tid >> 4;          // 16-lane group id, 0..63
    const int sub = tid & 15;
    const float* xbase = x + (size_t)(b * H_) * W_ * C_;
    for (int j = 0; j < (SR * W_ + 63) / 64; ++j) {
        const int ps = j * 64 + g;                  // staged position slot
        if (ps < SR * W_) {
            const int r  = ps / W_;
            const int cl = ps - r * W_;
            const int yy = y0 + r - HALO;
            if (yy >= 0 && yy < H_) {
                const nf4* xp = (const nf4*)(xbase + ((size_t)yy * W_ + cl) * C_);
                nf4 a0 = xp[sub];
                nf4 a1 = xp[sub + 16];
                nf4 a2 = xp[sub + 32];
                float s = ((a0[0]+a0[1]) + (a0[2]+a0[3]))
                        + ((a1[0]+a1[1]) + (a1[2]+a1[3]))
                        + ((a2[0]+a2[1]) + (a2[2]+a2[3]));
                float m0 = fmaxf(fmaxf(a0[0], a0[1]), fmaxf(a0[2], a0[3]));
                float m1 = fmaxf(fmaxf(a1[0], a1[1]), fmaxf(a1[2], a1[3]));
                float m2 = fmaxf(fmaxf(a2[0], a2[1]), fmaxf(a2[2], a2[3]));
                float m  = fmaxf(m0, fmaxf(m1, m2));
                #pragma unroll
                for (int off = 8; off > 0; off >>= 1) {
                    s += __shfl_xor(s, off);
                    m = fmaxf(m, __shfl_xor(m, off));
                }
                if (sub == 0)
                    sm[r][HALO + cl] = make_float2(s * (1.0f / (float)C_), m);
            }
        }
    }
    __syncthreads();

    // ---- phase 2: 7x7 conv + sigmoid (halo pre-zeroed, no bounds checks) ----
    if (tid < R_ * W_) {
        const int r  = tid / W_;
        const int cl = tid - r * W_;
        float acc = 0.0f;
        #pragma unroll
        for (int ky = 0; ky < 7; ++ky) {
            #pragma unroll
            for (int kx = 0; kx < 7; ++kx) {
                float2 am = sm[r + ky][cl + kx];
                acc = fmaf(am.x, sw[(ky * 7 + kx) * 2 + 0], acc);
                acc = fmaf(am.y, sw[(ky * 7 + kx) * 2 + 1], acc);
            }
        }
        satt[tid] = 1.0f / (1.0f + __expf(-acc));
    }
    __syncthreads();

    // ---- phase 3: out = x * att over the tile's 7 rows ----
    // 7*112*48 = 37632 float4; 36 full passes + 1 partial of 1024 threads
    const size_t base4 = (size_t)(b * H_ + y0) * W_ * C4;
    const nf4* xr   = (const nf4*)x + base4;
    nf4*       orow = (nf4*)out + base4;
    for (int f = tid; f < R_ * W_ * C4; f += NT_) {
        nf4 v = xr[f];                              // regular load: want cache hit
        v = v * satt[f / C4];
        __builtin_nontemporal_store(v, &orow[f]);   // dead data: don't pollute L3
    }
}

extern "C" void kernel_launch(void* const* d_in, const int* in_sizes, int n_in,
                              void* d_out, int out_size, void* d_ws, size_t ws_size,
                              hipStream_t stream) {
    const float* x = (const float*)d_in[0];
    const float* w = (const float*)d_in[1];
    float* out = (float*)d_out;
    fused_kernel<<<NBLK, NT_, 0, stream>>>(x, w, out);
}